// Round 1
// baseline (3064.878 us; speedup 1.0000x reference)
//
#include <hip/hip_runtime.h>
#include <math.h>

#define NTOK 2048
#define FDIM 2048
#define HDIM 4096
#define NEXP 8
#define MAXPAIR (NTOK * 2)   // each token picks exactly 2 experts

typedef _Float16 f16;
typedef _Float16 f16x4 __attribute__((ext_vector_type(4)));
typedef _Float16 f16x8 __attribute__((ext_vector_type(8)));
typedef float    f32x4 __attribute__((ext_vector_type(4)));

// ---------------- workspace layout (bytes) ----------------
// xh   : fp16 copy of x                [NTOK][FDIM]
// hbuf : fp16 silu(x@w1)*(x@w3)        [MAXPAIR+128][HDIM]  (padded rows for ragged tiles)
// ybuf : fp32 h@w2                     [MAXPAIR][FDIM]
// expert_tokens[NEXP][NTOK], counts[8], bases[8], tok_e/tok_pos/tok_w per token (2 each)
static constexpr size_t OFF_XH   = 0;
static constexpr size_t OFF_H    = OFF_XH + (size_t)NTOK * FDIM * 2;            // 8 MB
static constexpr size_t OFF_Y    = OFF_H + (size_t)(MAXPAIR + 128) * HDIM * 2;  // +33 MB
static constexpr size_t OFF_ET   = OFF_Y + (size_t)MAXPAIR * FDIM * 4;          // +32 MB
static constexpr size_t OFF_CNT  = OFF_ET + (size_t)NEXP * NTOK * 4;
static constexpr size_t OFF_BASE = OFF_CNT + 128;
static constexpr size_t OFF_TE   = OFF_BASE + 128;
static constexpr size_t OFF_TP   = OFF_TE + (size_t)NTOK * 2 * 4;
static constexpr size_t OFF_TW   = OFF_TP + (size_t)NTOK * 2 * 4;
// total ~73 MB

// ---------------- kernel 1: x fp32 -> fp16, zero counters ----------------
__global__ __launch_bounds__(256) void convert_zero_kernel(
    const float* __restrict__ x, f16* __restrict__ xh, int* __restrict__ counts)
{
    int i = blockIdx.x * 256 + threadIdx.x;        // over NTOK*FDIM/4
    float4 v = ((const float4*)x)[i];
    f16x4 h = { (f16)v.x, (f16)v.y, (f16)v.z, (f16)v.w };
    ((f16x4*)xh)[i] = h;
    if (i < NEXP) counts[i] = 0;
}

// ---------------- kernel 2: fp32 router, one wave per token ----------------
__global__ __launch_bounds__(64) void router_kernel(
    const float* __restrict__ x, const float* __restrict__ gw,
    int* __restrict__ counts, int* __restrict__ expert_tokens,
    int* __restrict__ tok_e, int* __restrict__ tok_pos, float* __restrict__ tok_w)
{
    const int t = blockIdx.x;
    const int l = threadIdx.x;
    const float* xr = x + (size_t)t * FDIM;
    float xv[FDIM / 64];
    #pragma unroll
    for (int i = 0; i < FDIM / 64; ++i) xv[i] = xr[i * 64 + l];

    float lg[NEXP];
    #pragma unroll
    for (int e = 0; e < NEXP; ++e) {
        const float* g = gw + (size_t)e * FDIM;
        float p = 0.f;
        #pragma unroll
        for (int i = 0; i < FDIM / 64; ++i) p = fmaf(xv[i], g[i * 64 + l], p);
        #pragma unroll
        for (int o = 32; o; o >>= 1) p += __shfl_xor(p, o);
        lg[e] = p;
    }
    if (l == 0) {
        float mx = lg[0];
        #pragma unroll
        for (int e = 1; e < NEXP; ++e) mx = fmaxf(mx, lg[e]);
        float pr[NEXP];
        #pragma unroll
        for (int e = 0; e < NEXP; ++e) pr[e] = expf(lg[e] - mx);
        // top-2 (lowest index on tie, matching jax.lax.top_k)
        int i0 = 0;
        #pragma unroll
        for (int e = 1; e < NEXP; ++e) if (pr[e] > pr[i0]) i0 = e;
        int i1 = (i0 == 0) ? 1 : 0;
        #pragma unroll
        for (int e = 0; e < NEXP; ++e) if (e != i0 && pr[e] > pr[i1]) i1 = e;
        float s = pr[i0] + pr[i1];
        float w0 = pr[i0] / s, w1 = pr[i1] / s;
        int p0 = atomicAdd(&counts[i0], 1);
        int p1 = atomicAdd(&counts[i1], 1);
        expert_tokens[i0 * NTOK + p0] = t;
        expert_tokens[i1 * NTOK + p1] = t;
        tok_e[2 * t] = i0;  tok_e[2 * t + 1] = i1;
        tok_pos[2 * t] = p0; tok_pos[2 * t + 1] = p1;
        tok_w[2 * t] = w0;  tok_w[2 * t + 1] = w1;
    }
}

// ---------------- kernel 3: exclusive prefix over 8 counts ----------------
__global__ void bases_kernel(const int* __restrict__ counts, int* __restrict__ bases)
{
    if (threadIdx.x == 0 && blockIdx.x == 0) {
        int s = 0;
        for (int e = 0; e < NEXP; ++e) { bases[e] = s; s += counts[e]; }
    }
}

// ---------------- kernel 4: GEMM1  h = silu(Xg@w1)*(Xg@w3), fp16 MFMA ----------------
// tile 128(M tokens) x 128(N hidden), BK=32, 256 thr = 4 waves (2x2 of 64x64)
__global__ __launch_bounds__(256) void gemm1_kernel(
    const f16* __restrict__ xh, const float* __restrict__ w1, const float* __restrict__ w3,
    const int* __restrict__ counts, const int* __restrict__ bases,
    const int* __restrict__ expert_tokens, f16* __restrict__ hbuf)
{
    const int e = blockIdx.x >> 4;
    const int mtile = blockIdx.x & 15;
    const int ntile = blockIdx.y;
    const int cnt = counts[e];
    const int m0 = mtile * 128;
    if (m0 >= cnt) return;
    const int rows = min(128, cnt - m0);
    const int base = bases[e];

    __shared__ f16 As[128 * 32];        // [m][k], row stride 32
    __shared__ f16 Bs1[128 * 36];       // [n][k], row stride 36 (pad: b64 writes stay 8B-aligned)
    __shared__ f16 Bs3[128 * 36];

    const int tid = threadIdx.x;
    const int lane = tid & 63;
    const int wave = tid >> 6;
    const int wm = wave >> 1, wn = wave & 1;

    // A staging: 2 chunks of 16B per thread; rows fixed across K-loop
    const f16* arow[2];
    #pragma unroll
    for (int q = 0; q < 2; ++q) {
        int chunk = q * 256 + tid;
        int row = chunk >> 2, kp = chunk & 3;
        int r = min(row, rows - 1);
        int token = expert_tokens[e * NTOK + m0 + r];
        arow[q] = xh + (size_t)token * FDIM + kp * 8;
    }
    // B staging: thread -> 4 consecutive n at n0, 4 consecutive k at kq*4
    const int n4 = tid & 31, kq = tid >> 5;
    const int n0 = n4 * 4;
    const float* b1p = w1 + (size_t)e * FDIM * HDIM + (size_t)(kq * 4) * HDIM + ntile * 128 + n0;
    const float* b3p = w3 + (size_t)e * FDIM * HDIM + (size_t)(kq * 4) * HDIM + ntile * 128 + n0;

    f32x4 acc1[4][4], acc3[4][4];
    #pragma unroll
    for (int i = 0; i < 4; ++i)
        #pragma unroll
        for (int j = 0; j < 4; ++j) {
            acc1[i][j] = (f32x4){0.f, 0.f, 0.f, 0.f};
            acc3[i][j] = (f32x4){0.f, 0.f, 0.f, 0.f};
        }

    for (int k0 = 0; k0 < FDIM; k0 += 32) {
        uint4 av[2];
        #pragma unroll
        for (int q = 0; q < 2; ++q) av[q] = *(const uint4*)(arow[q] + k0);
        float4 r1[4], r3[4];
        #pragma unroll
        for (int kk = 0; kk < 4; ++kk) {
            r1[kk] = *(const float4*)(b1p + (size_t)(k0 + kk) * HDIM);
            r3[kk] = *(const float4*)(b3p + (size_t)(k0 + kk) * HDIM);
        }
        __syncthreads();   // previous iter's frag reads done
        #pragma unroll
        for (int q = 0; q < 2; ++q)
            *(uint4*)&As[(q * 256 + tid) * 8] = av[q];
        #pragma unroll
        for (int i = 0; i < 4; ++i) {
            f16x4 v1 = { (f16)((const float*)&r1[0])[i], (f16)((const float*)&r1[1])[i],
                         (f16)((const float*)&r1[2])[i], (f16)((const float*)&r1[3])[i] };
            f16x4 v3 = { (f16)((const float*)&r3[0])[i], (f16)((const float*)&r3[1])[i],
                         (f16)((const float*)&r3[2])[i], (f16)((const float*)&r3[3])[i] };
            *(f16x4*)&Bs1[(n0 + i) * 36 + kq * 4] = v1;
            *(f16x4*)&Bs3[(n0 + i) * 36 + kq * 4] = v3;
        }
        __syncthreads();

        f16x8 af[4];
        #pragma unroll
        for (int i = 0; i < 4; ++i)
            af[i] = *(const f16x8*)&As[(wm * 64 + i * 16 + (lane & 15)) * 32 + (lane >> 4) * 8];
        #pragma unroll
        for (int j = 0; j < 4; ++j) {
            const int nn = (wn * 64 + j * 16 + (lane & 15)) * 36 + (lane >> 4) * 8;
            f16x4 b1a = *(const f16x4*)&Bs1[nn];
            f16x4 b1b = *(const f16x4*)&Bs1[nn + 4];
            f16x8 bf1 = __builtin_shufflevector(b1a, b1b, 0, 1, 2, 3, 4, 5, 6, 7);
            f16x4 b3a = *(const f16x4*)&Bs3[nn];
            f16x4 b3b = *(const f16x4*)&Bs3[nn + 4];
            f16x8 bf3 = __builtin_shufflevector(b3a, b3b, 0, 1, 2, 3, 4, 5, 6, 7);
            #pragma unroll
            for (int i = 0; i < 4; ++i) {
                acc1[i][j] = __builtin_amdgcn_mfma_f32_16x16x32_f16(af[i], bf1, acc1[i][j], 0, 0, 0);
                acc3[i][j] = __builtin_amdgcn_mfma_f32_16x16x32_f16(af[i], bf3, acc3[i][j], 0, 0, 0);
            }
        }
    }

    // epilogue: h = silu(a1)*a3 -> fp16   (C/D layout: col=lane&15, row=(lane>>4)*4+r)
    #pragma unroll
    for (int i = 0; i < 4; ++i) {
        int rl0 = wm * 64 + i * 16 + ((lane >> 4) << 2);
        #pragma unroll
        for (int r = 0; r < 4; ++r) {
            int rl = rl0 + r;
            if (rl < rows) {
                size_t ro = (size_t)(base + m0 + rl) * HDIM + ntile * 128 + wn * 64 + (lane & 15);
                #pragma unroll
                for (int j = 0; j < 4; ++j) {
                    float a1 = acc1[i][j][r];
                    float a3 = acc3[i][j][r];
                    float hv = (a1 / (1.f + expf(-a1))) * a3;
                    hbuf[ro + j * 16] = (f16)hv;
                }
            }
        }
    }
}

// ---------------- kernel 5: GEMM2  y = h @ w2, fp16 MFMA, fp32 out ----------------
__global__ __launch_bounds__(256) void gemm2_kernel(
    const f16* __restrict__ hbuf, const float* __restrict__ w2,
    const int* __restrict__ counts, const int* __restrict__ bases,
    float* __restrict__ ybuf)
{
    const int e = blockIdx.x >> 4;
    const int mtile = blockIdx.x & 15;
    const int ntile = blockIdx.y;       // FDIM/128 = 16
    const int cnt = counts[e];
    const int m0 = mtile * 128;
    if (m0 >= cnt) return;
    const int rows = min(128, cnt - m0);
    const int base = bases[e];

    __shared__ f16 As[128 * 32];
    __shared__ f16 Bs[128 * 36];

    const int tid = threadIdx.x;
    const int lane = tid & 63;
    const int wave = tid >> 6;
    const int wm = wave >> 1, wn = wave & 1;

    const f16* arow[2];
    #pragma unroll
    for (int q = 0; q < 2; ++q) {
        int chunk = q * 256 + tid;
        int row = chunk >> 2, kp = chunk & 3;
        arow[q] = hbuf + (size_t)(base + m0 + row) * HDIM + kp * 8;  // padding rows finite (poison fp16)
    }
    const int n4 = tid & 31, kq = tid >> 5;
    const int n0 = n4 * 4;
    const float* b2p = w2 + (size_t)e * HDIM * FDIM + (size_t)(kq * 4) * FDIM + ntile * 128 + n0;

    f32x4 acc[4][4];
    #pragma unroll
    for (int i = 0; i < 4; ++i)
        #pragma unroll
        for (int j = 0; j < 4; ++j) acc[i][j] = (f32x4){0.f, 0.f, 0.f, 0.f};

    for (int k0 = 0; k0 < HDIM; k0 += 32) {
        uint4 av[2];
        #pragma unroll
        for (int q = 0; q < 2; ++q) av[q] = *(const uint4*)(arow[q] + k0);
        float4 rb[4];
        #pragma unroll
        for (int kk = 0; kk < 4; ++kk)
            rb[kk] = *(const float4*)(b2p + (size_t)(k0 + kk) * FDIM);
        __syncthreads();
        #pragma unroll
        for (int q = 0; q < 2; ++q)
            *(uint4*)&As[(q * 256 + tid) * 8] = av[q];
        #pragma unroll
        for (int i = 0; i < 4; ++i) {
            f16x4 v = { (f16)((const float*)&rb[0])[i], (f16)((const float*)&rb[1])[i],
                        (f16)((const float*)&rb[2])[i], (f16)((const float*)&rb[3])[i] };
            *(f16x4*)&Bs[(n0 + i) * 36 + kq * 4] = v;
        }
        __syncthreads();

        f16x8 af[4];
        #pragma unroll
        for (int i = 0; i < 4; ++i)
            af[i] = *(const f16x8*)&As[(wm * 64 + i * 16 + (lane & 15)) * 32 + (lane >> 4) * 8];
        #pragma unroll
        for (int j = 0; j < 4; ++j) {
            const int nn = (wn * 64 + j * 16 + (lane & 15)) * 36 + (lane >> 4) * 8;
            f16x4 ba = *(const f16x4*)&Bs[nn];
            f16x4 bb = *(const f16x4*)&Bs[nn + 4];
            f16x8 bf = __builtin_shufflevector(ba, bb, 0, 1, 2, 3, 4, 5, 6, 7);
            #pragma unroll
            for (int i = 0; i < 4; ++i)
                acc[i][j] = __builtin_amdgcn_mfma_f32_16x16x32_f16(af[i], bf, acc[i][j], 0, 0, 0);
        }
    }

    #pragma unroll
    for (int i = 0; i < 4; ++i) {
        int rl0 = wm * 64 + i * 16 + ((lane >> 4) << 2);
        #pragma unroll
        for (int r = 0; r < 4; ++r) {
            int rl = rl0 + r;
            if (rl < rows) {
                size_t ro = (size_t)(base + m0 + rl) * FDIM + ntile * 128 + wn * 64 + (lane & 15);
                #pragma unroll
                for (int j = 0; j < 4; ++j)
                    ybuf[ro + j * 16] = acc[i][j][r];
            }
        }
    }
}

// ---------------- kernel 6: out[t] = w0*y[slot0] + w1*y[slot1] ----------------
__global__ __launch_bounds__(256) void combine_kernel(
    const float* __restrict__ ybuf, const int* __restrict__ tok_e,
    const int* __restrict__ tok_pos, const float* __restrict__ tok_w,
    const int* __restrict__ bases, float* __restrict__ out)
{
    int idx = blockIdx.x * 256 + threadIdx.x;      // NTOK * FDIM/4
    int t = idx >> 9;                              // FDIM/4 = 512
    int f = (idx & 511) << 2;
    int e0 = tok_e[2 * t], e1 = tok_e[2 * t + 1];
    int s0 = bases[e0] + tok_pos[2 * t];
    int s1 = bases[e1] + tok_pos[2 * t + 1];
    float w0 = tok_w[2 * t], w1 = tok_w[2 * t + 1];
    float4 y0 = *(const float4*)&ybuf[(size_t)s0 * FDIM + f];
    float4 y1 = *(const float4*)&ybuf[(size_t)s1 * FDIM + f];
    float4 o = { w0 * y0.x + w1 * y1.x, w0 * y0.y + w1 * y1.y,
                 w0 * y0.z + w1 * y1.z, w0 * y0.w + w1 * y1.w };
    *(float4*)&out[(size_t)t * FDIM + f] = o;
}

// ---------------- launcher ----------------
extern "C" void kernel_launch(void* const* d_in, const int* in_sizes, int n_in,
                              void* d_out, int out_size, void* d_ws, size_t ws_size,
                              hipStream_t stream)
{
    const float* x  = (const float*)d_in[0];   // hidden_states [2,1024,2048]
    const float* gw = (const float*)d_in[1];   // gate_w [8,2048]
    const float* w1 = (const float*)d_in[2];   // [8,2048,4096]
    const float* w2 = (const float*)d_in[3];   // [8,4096,2048]
    const float* w3 = (const float*)d_in[4];   // [8,2048,4096]
    float* out = (float*)d_out;

    char* ws = (char*)d_ws;
    f16*   xh            = (f16*)(ws + OFF_XH);
    f16*   hbuf          = (f16*)(ws + OFF_H);
    float* ybuf          = (float*)(ws + OFF_Y);
    int*   expert_tokens = (int*)(ws + OFF_ET);
    int*   counts        = (int*)(ws + OFF_CNT);
    int*   bases         = (int*)(ws + OFF_BASE);
    int*   tok_e         = (int*)(ws + OFF_TE);
    int*   tok_pos       = (int*)(ws + OFF_TP);
    float* tok_w         = (float*)(ws + OFF_TW);

    convert_zero_kernel<<<NTOK * FDIM / 4 / 256, 256, 0, stream>>>(x, xh, counts);
    router_kernel<<<NTOK, 64, 0, stream>>>(x, gw, counts, expert_tokens, tok_e, tok_pos, tok_w);
    bases_kernel<<<1, 64, 0, stream>>>(counts, bases);
    gemm1_kernel<<<dim3(NEXP * 16, HDIM / 128), 256, 0, stream>>>(
        xh, w1, w3, counts, bases, expert_tokens, hbuf);
    gemm2_kernel<<<dim3(NEXP * 16, FDIM / 128), 256, 0, stream>>>(
        hbuf, w2, counts, bases, ybuf);
    combine_kernel<<<NTOK * FDIM / 4 / 256, 256, 0, stream>>>(
        ybuf, tok_e, tok_pos, tok_w, bases, out);
}

// Round 2
// 2843.074 us; speedup vs baseline: 1.0780x; 1.0780x over previous
//
#include <hip/hip_runtime.h>
#include <math.h>

#define NTOK 2048
#define FDIM 2048
#define HDIM 4096
#define NEXP 8
#define MAXPAIR (NTOK * 2)   // each token picks exactly 2 experts

typedef _Float16 f16;
typedef _Float16 f16x2 __attribute__((ext_vector_type(2)));
typedef _Float16 f16x4 __attribute__((ext_vector_type(4)));
typedef _Float16 f16x8 __attribute__((ext_vector_type(8)));
typedef float    f32x4 __attribute__((ext_vector_type(4)));

// ---------------- workspace layout (bytes) ----------------
static constexpr size_t OFF_XH   = 0;
static constexpr size_t OFF_H    = OFF_XH + (size_t)NTOK * FDIM * 2;            // 8 MB
static constexpr size_t OFF_Y    = OFF_H + (size_t)(MAXPAIR + 128) * HDIM * 2;  // +33 MB
static constexpr size_t OFF_ET   = OFF_Y + (size_t)MAXPAIR * FDIM * 4;          // +32 MB
static constexpr size_t OFF_CNT  = OFF_ET + (size_t)NEXP * NTOK * 4;
static constexpr size_t OFF_BASE = OFF_CNT + 128;
static constexpr size_t OFF_TE   = OFF_BASE + 128;
static constexpr size_t OFF_TP   = OFF_TE + (size_t)NTOK * 2 * 4;
static constexpr size_t OFF_TW   = OFF_TP + (size_t)NTOK * 2 * 4;
// total ~73 MB

// ---------------- kernel 1: x fp32 -> fp16, zero counters ----------------
__global__ __launch_bounds__(256) void convert_zero_kernel(
    const float* __restrict__ x, f16* __restrict__ xh, int* __restrict__ counts)
{
    int i = blockIdx.x * 256 + threadIdx.x;        // over NTOK*FDIM/4
    float4 v = ((const float4*)x)[i];
    f16x4 h = { (f16)v.x, (f16)v.y, (f16)v.z, (f16)v.w };
    ((f16x4*)xh)[i] = h;
    if (i < NEXP) counts[i] = 0;
}

// ---------------- kernel 2: fp32 router, one wave per token ----------------
__global__ __launch_bounds__(64) void router_kernel(
    const float* __restrict__ x, const float* __restrict__ gw,
    int* __restrict__ counts, int* __restrict__ expert_tokens,
    int* __restrict__ tok_e, int* __restrict__ tok_pos, float* __restrict__ tok_w)
{
    const int t = blockIdx.x;
    const int l = threadIdx.x;
    const float* xr = x + (size_t)t * FDIM;
    float xv[FDIM / 64];
    #pragma unroll
    for (int i = 0; i < FDIM / 64; ++i) xv[i] = xr[i * 64 + l];

    float lg[NEXP];
    #pragma unroll
    for (int e = 0; e < NEXP; ++e) {
        const float* g = gw + (size_t)e * FDIM;
        float p = 0.f;
        #pragma unroll
        for (int i = 0; i < FDIM / 64; ++i) p = fmaf(xv[i], g[i * 64 + l], p);
        #pragma unroll
        for (int o = 32; o; o >>= 1) p += __shfl_xor(p, o);
        lg[e] = p;
    }
    if (l == 0) {
        float mx = lg[0];
        #pragma unroll
        for (int e = 1; e < NEXP; ++e) mx = fmaxf(mx, lg[e]);
        float pr[NEXP];
        #pragma unroll
        for (int e = 0; e < NEXP; ++e) pr[e] = expf(lg[e] - mx);
        int i0 = 0;
        #pragma unroll
        for (int e = 1; e < NEXP; ++e) if (pr[e] > pr[i0]) i0 = e;
        int i1 = (i0 == 0) ? 1 : 0;
        #pragma unroll
        for (int e = 0; e < NEXP; ++e) if (e != i0 && pr[e] > pr[i1]) i1 = e;
        float s = pr[i0] + pr[i1];
        float w0 = pr[i0] / s, w1 = pr[i1] / s;
        int p0 = atomicAdd(&counts[i0], 1);
        int p1 = atomicAdd(&counts[i1], 1);
        expert_tokens[i0 * NTOK + p0] = t;
        expert_tokens[i1 * NTOK + p1] = t;
        tok_e[2 * t] = i0;  tok_e[2 * t + 1] = i1;
        tok_pos[2 * t] = p0; tok_pos[2 * t + 1] = p1;
        tok_w[2 * t] = w0;  tok_w[2 * t + 1] = w1;
    }
}

// ---------------- kernel 3: exclusive prefix over 8 counts ----------------
__global__ void bases_kernel(const int* __restrict__ counts, int* __restrict__ bases)
{
    if (threadIdx.x == 0 && blockIdx.x == 0) {
        int s = 0;
        for (int e = 0; e < NEXP; ++e) { bases[e] = s; s += counts[e]; }
    }
}

// ---------------- kernel 4: GEMM1  h = silu(Xg@w1)*(Xg@w3), fp16 MFMA ----------------
// tile 128(M) x 64(N), BK=32, 256 thr = 4 waves (2m x 2n of 64x32)
// register double-buffer: loads for k+32 issued before the MFMA phase of k
__global__ __launch_bounds__(256) void gemm1_kernel(
    const f16* __restrict__ xh, const float* __restrict__ w1, const float* __restrict__ w3,
    const int* __restrict__ counts, const int* __restrict__ bases,
    const int* __restrict__ expert_tokens, f16* __restrict__ hbuf)
{
    const int mtile = blockIdx.x & 15;          // fast dim: same-B blocks adjacent
    const int ntile = blockIdx.x >> 4;          // HDIM/64 = 64
    const int e = blockIdx.y;
    const int cnt = counts[e];
    const int m0 = mtile * 128;
    if (m0 >= cnt) return;
    const int rows = min(128, cnt - m0);
    const int base = bases[e];

    __shared__ f16 As[128 * 32];        // [m][k], row stride 32
    __shared__ f16 Bs1[64 * 36];        // [n][k], stride 36 (pad keeps 8B align for b64 reads)
    __shared__ f16 Bs3[64 * 36];

    const int tid = threadIdx.x;
    const int lane = tid & 63;
    const int wave = tid >> 6;
    const int wm = wave >> 1, wn = wave & 1;

    // A staging: 2 chunks of 16B per thread
    const f16* arow[2];
    #pragma unroll
    for (int q = 0; q < 2; ++q) {
        int chunk = q * 256 + tid;
        int row = chunk >> 2, kp = chunk & 3;
        int r = min(row, rows - 1);
        int token = expert_tokens[e * NTOK + m0 + r];
        arow[q] = xh + (size_t)token * FDIM + kp * 8;
    }
    // B staging: thread (n4=tid&15 -> 4 n), (kq=tid>>4 -> rows kq*2, kq*2+1)
    const int n4 = tid & 15, kq = tid >> 4;
    const int n0 = n4 * 4;
    const float* b1p = w1 + (size_t)e * FDIM * HDIM + (size_t)(kq * 2) * HDIM + ntile * 64 + n0;
    const float* b3p = w3 + (size_t)e * FDIM * HDIM + (size_t)(kq * 2) * HDIM + ntile * 64 + n0;

    f32x4 acc1[4][2], acc3[4][2];
    #pragma unroll
    for (int i = 0; i < 4; ++i)
        #pragma unroll
        for (int j = 0; j < 2; ++j) {
            acc1[i][j] = (f32x4){0.f, 0.f, 0.f, 0.f};
            acc3[i][j] = (f32x4){0.f, 0.f, 0.f, 0.f};
        }

    // ---- preload k0 = 0 ----
    uint4 av[2];
    float4 r1v[2], r3v[2];
    #pragma unroll
    for (int q = 0; q < 2; ++q) av[q] = *(const uint4*)(arow[q]);
    #pragma unroll
    for (int kk = 0; kk < 2; ++kk) {
        r1v[kk] = *(const float4*)(b1p + (size_t)kk * HDIM);
        r3v[kk] = *(const float4*)(b3p + (size_t)kk * HDIM);
    }

    for (int k0 = 0; k0 < FDIM; k0 += 32) {
        __syncthreads();   // previous iter's frag reads done
        #pragma unroll
        for (int q = 0; q < 2; ++q)
            *(uint4*)&As[(q * 256 + tid) * 8] = av[q];
        #pragma unroll
        for (int i = 0; i < 4; ++i) {
            f16x2 v1 = { (f16)((const float*)&r1v[0])[i], (f16)((const float*)&r1v[1])[i] };
            f16x2 v3 = { (f16)((const float*)&r3v[0])[i], (f16)((const float*)&r3v[1])[i] };
            *(f16x2*)&Bs1[(n0 + i) * 36 + kq * 2] = v1;
            *(f16x2*)&Bs3[(n0 + i) * 36 + kq * 2] = v3;
        }
        __syncthreads();

        // ---- issue next-iter loads (overlap with MFMA phase) ----
        if (k0 + 32 < FDIM) {
            const int kn = k0 + 32;
            #pragma unroll
            for (int q = 0; q < 2; ++q) av[q] = *(const uint4*)(arow[q] + kn);
            #pragma unroll
            for (int kk = 0; kk < 2; ++kk) {
                r1v[kk] = *(const float4*)(b1p + (size_t)(kn + kk) * HDIM);
                r3v[kk] = *(const float4*)(b3p + (size_t)(kn + kk) * HDIM);
            }
        }

        f16x8 af[4];
        #pragma unroll
        for (int i = 0; i < 4; ++i)
            af[i] = *(const f16x8*)&As[(wm * 64 + i * 16 + (lane & 15)) * 32 + (lane >> 4) * 8];
        #pragma unroll
        for (int j = 0; j < 2; ++j) {
            const int nn = (wn * 32 + j * 16 + (lane & 15)) * 36 + (lane >> 4) * 8;
            f16x4 b1a = *(const f16x4*)&Bs1[nn];
            f16x4 b1b = *(const f16x4*)&Bs1[nn + 4];
            f16x8 bf1 = __builtin_shufflevector(b1a, b1b, 0, 1, 2, 3, 4, 5, 6, 7);
            f16x4 b3a = *(const f16x4*)&Bs3[nn];
            f16x4 b3b = *(const f16x4*)&Bs3[nn + 4];
            f16x8 bf3 = __builtin_shufflevector(b3a, b3b, 0, 1, 2, 3, 4, 5, 6, 7);
            #pragma unroll
            for (int i = 0; i < 4; ++i) {
                acc1[i][j] = __builtin_amdgcn_mfma_f32_16x16x32_f16(af[i], bf1, acc1[i][j], 0, 0, 0);
                acc3[i][j] = __builtin_amdgcn_mfma_f32_16x16x32_f16(af[i], bf3, acc3[i][j], 0, 0, 0);
            }
        }
    }

    // epilogue: h = silu(a1)*a3 -> fp16   (C/D: col=lane&15, row=(lane>>4)*4+r)
    #pragma unroll
    for (int i = 0; i < 4; ++i) {
        int rl0 = wm * 64 + i * 16 + ((lane >> 4) << 2);
        #pragma unroll
        for (int r = 0; r < 4; ++r) {
            int rl = rl0 + r;
            if (rl < rows) {
                size_t ro = (size_t)(base + m0 + rl) * HDIM + ntile * 64 + wn * 32 + (lane & 15);
                #pragma unroll
                for (int j = 0; j < 2; ++j) {
                    float a1 = acc1[i][j][r];
                    float a3 = acc3[i][j][r];
                    float hv = (a1 / (1.f + expf(-a1))) * a3;
                    hbuf[ro + j * 16] = (f16)hv;
                }
            }
        }
    }
}

// ---------------- kernel 5: GEMM2  y = h @ w2, fp16 MFMA, fp32 out ----------------
// tile 128x128, BK=32, register double-buffer
__global__ __launch_bounds__(256) void gemm2_kernel(
    const f16* __restrict__ hbuf, const float* __restrict__ w2,
    const int* __restrict__ counts, const int* __restrict__ bases,
    float* __restrict__ ybuf)
{
    const int mtile = blockIdx.x & 15;
    const int ntile = blockIdx.x >> 4;          // FDIM/128 = 16
    const int e = blockIdx.y;
    const int cnt = counts[e];
    const int m0 = mtile * 128;
    if (m0 >= cnt) return;
    const int rows = min(128, cnt - m0);
    const int base = bases[e];

    __shared__ f16 As[128 * 32];
    __shared__ f16 Bs[128 * 36];

    const int tid = threadIdx.x;
    const int lane = tid & 63;
    const int wave = tid >> 6;
    const int wm = wave >> 1, wn = wave & 1;

    const f16* arow[2];
    #pragma unroll
    for (int q = 0; q < 2; ++q) {
        int chunk = q * 256 + tid;
        int row = chunk >> 2, kp = chunk & 3;
        int r = min(row, rows - 1);            // clamp: never read poison rows
        arow[q] = hbuf + (size_t)(base + m0 + r) * HDIM + kp * 8;
    }
    const int n4 = tid & 31, kq = tid >> 5;
    const int n0 = n4 * 4;
    const float* b2p = w2 + (size_t)e * HDIM * FDIM + (size_t)(kq * 4) * FDIM + ntile * 128 + n0;

    f32x4 acc[4][4];
    #pragma unroll
    for (int i = 0; i < 4; ++i)
        #pragma unroll
        for (int j = 0; j < 4; ++j) acc[i][j] = (f32x4){0.f, 0.f, 0.f, 0.f};

    uint4 av[2];
    float4 rb[4];
    #pragma unroll
    for (int q = 0; q < 2; ++q) av[q] = *(const uint4*)(arow[q]);
    #pragma unroll
    for (int kk = 0; kk < 4; ++kk) rb[kk] = *(const float4*)(b2p + (size_t)kk * FDIM);

    for (int k0 = 0; k0 < HDIM; k0 += 32) {
        __syncthreads();
        #pragma unroll
        for (int q = 0; q < 2; ++q)
            *(uint4*)&As[(q * 256 + tid) * 8] = av[q];
        #pragma unroll
        for (int i = 0; i < 4; ++i) {
            f16x4 v = { (f16)((const float*)&rb[0])[i], (f16)((const float*)&rb[1])[i],
                        (f16)((const float*)&rb[2])[i], (f16)((const float*)&rb[3])[i] };
            *(f16x4*)&Bs[(n0 + i) * 36 + kq * 4] = v;
        }
        __syncthreads();

        if (k0 + 32 < HDIM) {
            const int kn = k0 + 32;
            #pragma unroll
            for (int q = 0; q < 2; ++q) av[q] = *(const uint4*)(arow[q] + kn);
            #pragma unroll
            for (int kk = 0; kk < 4; ++kk)
                rb[kk] = *(const float4*)(b2p + (size_t)(kn + kk) * FDIM);
        }

        f16x8 af[4];
        #pragma unroll
        for (int i = 0; i < 4; ++i)
            af[i] = *(const f16x8*)&As[(wm * 64 + i * 16 + (lane & 15)) * 32 + (lane >> 4) * 8];
        #pragma unroll
        for (int j = 0; j < 4; ++j) {
            const int nn = (wn * 64 + j * 16 + (lane & 15)) * 36 + (lane >> 4) * 8;
            f16x4 ba = *(const f16x4*)&Bs[nn];
            f16x4 bb = *(const f16x4*)&Bs[nn + 4];
            f16x8 bf = __builtin_shufflevector(ba, bb, 0, 1, 2, 3, 4, 5, 6, 7);
            #pragma unroll
            for (int i = 0; i < 4; ++i)
                acc[i][j] = __builtin_amdgcn_mfma_f32_16x16x32_f16(af[i], bf, acc[i][j], 0, 0, 0);
        }
    }

    #pragma unroll
    for (int i = 0; i < 4; ++i) {
        int rl0 = wm * 64 + i * 16 + ((lane >> 4) << 2);
        #pragma unroll
        for (int r = 0; r < 4; ++r) {
            int rl = rl0 + r;
            if (rl < rows) {
                size_t ro = (size_t)(base + m0 + rl) * FDIM + ntile * 128 + wn * 64 + (lane & 15);
                #pragma unroll
                for (int j = 0; j < 4; ++j)
                    ybuf[ro + j * 16] = acc[i][j][r];
            }
        }
    }
}

// ---------------- kernel 6: out[t] = w0*y[slot0] + w1*y[slot1] ----------------
__global__ __launch_bounds__(256) void combine_kernel(
    const float* __restrict__ ybuf, const int* __restrict__ tok_e,
    const int* __restrict__ tok_pos, const float* __restrict__ tok_w,
    const int* __restrict__ bases, float* __restrict__ out)
{
    int idx = blockIdx.x * 256 + threadIdx.x;      // NTOK * FDIM/4
    int t = idx >> 9;                              // FDIM/4 = 512
    int f = (idx & 511) << 2;
    int e0 = tok_e[2 * t], e1 = tok_e[2 * t + 1];
    int s0 = bases[e0] + tok_pos[2 * t];
    int s1 = bases[e1] + tok_pos[2 * t + 1];
    float w0 = tok_w[2 * t], w1 = tok_w[2 * t + 1];
    float4 y0 = *(const float4*)&ybuf[(size_t)s0 * FDIM + f];
    float4 y1 = *(const float4*)&ybuf[(size_t)s1 * FDIM + f];
    float4 o = { w0 * y0.x + w1 * y1.x, w0 * y0.y + w1 * y1.y,
                 w0 * y0.z + w1 * y1.z, w0 * y0.w + w1 * y1.w };
    *(float4*)&out[(size_t)t * FDIM + f] = o;
}

// ---------------- launcher ----------------
extern "C" void kernel_launch(void* const* d_in, const int* in_sizes, int n_in,
                              void* d_out, int out_size, void* d_ws, size_t ws_size,
                              hipStream_t stream)
{
    const float* x  = (const float*)d_in[0];
    const float* gw = (const float*)d_in[1];
    const float* w1 = (const float*)d_in[2];
    const float* w2 = (const float*)d_in[3];
    const float* w3 = (const float*)d_in[4];
    float* out = (float*)d_out;

    char* ws = (char*)d_ws;
    f16*   xh            = (f16*)(ws + OFF_XH);
    f16*   hbuf          = (f16*)(ws + OFF_H);
    float* ybuf          = (float*)(ws + OFF_Y);
    int*   expert_tokens = (int*)(ws + OFF_ET);
    int*   counts        = (int*)(ws + OFF_CNT);
    int*   bases         = (int*)(ws + OFF_BASE);
    int*   tok_e         = (int*)(ws + OFF_TE);
    int*   tok_pos       = (int*)(ws + OFF_TP);
    float* tok_w         = (float*)(ws + OFF_TW);

    convert_zero_kernel<<<NTOK * FDIM / 4 / 256, 256, 0, stream>>>(x, xh, counts);
    router_kernel<<<NTOK, 64, 0, stream>>>(x, gw, counts, expert_tokens, tok_e, tok_pos, tok_w);
    bases_kernel<<<1, 64, 0, stream>>>(counts, bases);
    gemm1_kernel<<<dim3(16 * (HDIM / 64), NEXP), 256, 0, stream>>>(
        xh, w1, w3, counts, bases, expert_tokens, hbuf);
    gemm2_kernel<<<dim3(16 * (FDIM / 128), NEXP), 256, 0, stream>>>(
        hbuf, w2, counts, bases, ybuf);
    combine_kernel<<<NTOK * FDIM / 4 / 256, 256, 0, stream>>>(
        ybuf, tok_e, tok_pos, tok_w, bases, out);
}